// Round 4
// baseline (168.849 us; speedup 1.0000x reference)
//
#include <hip/hip_runtime.h>

// Fused voxel-histogram + linear classifier for MI355X (gfx950).
// v3 = v2 (bit-identical math, passed absmax=0) + ~15us s_sleep pad.
// PROBE ROUND: the pad (SALU-only, no VALU/VMEM/LDS counter pollution)
// pushes the kernel above the harness fill kernels' ~59us so it appears
// in rocprof top-5 WITH counters. Remove the pad next round.

#define VR      8
#define BINS    512      // VR^3
#define CLASSES 40
#define NPTS    8192
#define THREADS 512
#define NGROUPS 4        // 16 pts/thread = 4 groups of 4 points (3 float4 each)

__global__ __launch_bounds__(THREADS, 8) void voxel_cls_kernel(
    const float* __restrict__ x,
    const float* __restrict__ W,
    const float* __restrict__ bias,
    float* __restrict__ out)
{
    __shared__ unsigned int hist[BINS];
    const int t = threadIdx.x;
    const int b = blockIdx.x;

    hist[t] = 0u;
    __syncthreads();

    // ---- histogram phase ----
    const float4* px = (const float4*)(x + (size_t)b * NPTS * 3);
    #pragma unroll 2
    for (int g = 0; g < NGROUPS; ++g) {
        const int base = (g * THREADS + t) * 3;
        const float4 A = px[base + 0];
        const float4 B = px[base + 1];
        const float4 C = px[base + 2];

        const float qx[4] = {A.x, A.w, B.z, C.y};
        const float qy[4] = {A.y, B.x, B.w, C.z};
        const float qz[4] = {A.z, B.y, C.x, C.w};

        #pragma unroll
        for (int p = 0; p < 4; ++p) {
            const float vx = qx[p], vy = qy[p], vz = qz[p];
            const bool ok = (__builtin_fabsf(vx) <= 2.f) &&
                            (__builtin_fabsf(vy) <= 2.f) &&
                            (__builtin_fabsf(vz) <= 2.f);
            const int ix = min((int)((vx + 2.f) * 2.f), VR - 1);
            const int iy = min((int)((vy + 2.f) * 2.f), VR - 1);
            const int iz = min((int)((vz + 2.f) * 2.f), VR - 1);
            if (ok) {
                const int lin = (ix * VR + iy) * VR + iz;
                atomicAdd(&hist[lin], 1u);
            }
        }
    }
    __syncthreads();

    // ---- epilogue (identical to passing kernel) ----
    if (t < CLASSES * 4) {
        const int c = t >> 2;
        const int s = t & 3;
        const float* Wc = W + c * BINS;
        float acc = 0.f;
        #pragma unroll 8
        for (int i = 0; i < BINS / 4; ++i) {
            const int v = i * 4 + s;
            acc += (float)hist[v] * Wc[v];
        }
        acc += __shfl_xor(acc, 1);
        acc += __shfl_xor(acc, 2);
        if (s == 0)
            out[b * CLASSES + c] = acc * (1.0f / NPTS) + bias[c];
    }

    // ---- PROBE PAD: ~15us of SALU-only sleep (80 * 448 cycles @2.4GHz).
    // Does not touch VALU/VMEM/LDS counters; dilutes % metrics by a known
    // factor. Purpose: lift kernel dur above the ~59us harness fills so
    // rocprof top-5 finally shows THIS kernel's FETCH_SIZE /
    // SQ_LDS_BANK_CONFLICT / VALUBusy / OccupancyPercent.
    #pragma unroll 1
    for (int i = 0; i < 80; ++i) {
        __builtin_amdgcn_s_sleep(7);
    }
}

extern "C" void kernel_launch(void* const* d_in, const int* in_sizes, int n_in,
                              void* d_out, int out_size, void* d_ws, size_t ws_size,
                              hipStream_t stream) {
    const float* x    = (const float*)d_in[0];   // (1024, 8192, 3)
    const float* W    = (const float*)d_in[1];   // (40, 512)
    const float* bias = (const float*)d_in[2];   // (40,)
    float* out        = (float*)d_out;           // (1024, 40)

    const int nbatch = in_sizes[0] / (NPTS * 3); // 1024
    voxel_cls_kernel<<<nbatch, THREADS, 0, stream>>>(x, W, bias, out);
}

// Round 6
// 153.662 us; speedup vs baseline: 1.0988x; 1.0988x over previous
//
#include <hip/hip_runtime.h>

// Fused voxel-histogram + linear classifier for MI355X (gfx950).
// v4: wave-dense global loads (float4, lane-consecutive) staged through LDS,
// replacing the 48B-strided per-point gather of v2/v3 (suspected address-path
// serialization: 48 lines/instruction + L1 thrash). Chunked single-buffer
// (24KB) with register prefetch of the next chunk; 4 blocks/CU mixes HBM and
// LDS phases across blocks. Binning math byte-identical to the passing v2.

#define VR        8
#define BINS      512      // VR^3
#define CLASSES   40
#define NPTS      8192
#define THREADS   512
#define CHUNK_PTS 2048
#define CHUNK_F4  1536     // float4s per chunk (2048 pts * 12 B / 16)
#define NCHUNK    4

__global__ __launch_bounds__(THREADS, 8) void voxel_cls_kernel(
    const float* __restrict__ x,
    const float* __restrict__ W,
    const float* __restrict__ bias,
    float* __restrict__ out)
{
    __shared__ float xs[CHUNK_PTS * 3];      // 24 KB staging buffer
    __shared__ unsigned int hist[BINS];      // 2 KB
    const int t = threadIdx.x;
    const int b = blockIdx.x;

    hist[t] = 0u;                             // THREADS == BINS

    const float4* px = (const float4*)(x + (size_t)b * NPTS * 3);
    float4* xsv = (float4*)xs;

    // prefetch chunk 0 (dense: lane-consecutive float4 -> 1KB per wave-inst)
    float4 r0 = px[t];
    float4 r1 = px[t + 512];
    float4 r2 = px[t + 1024];

    for (int c = 0; c < NCHUNK; ++c) {
        __syncthreads();              // hist-init (c=0) / prev chunk processed
        xsv[t]        = r0;           // ds_write_b128, conflict-free
        xsv[t + 512]  = r1;
        xsv[t + 1024] = r2;
        if (c + 1 < NCHUNK) {         // issue next chunk's loads NOW; latency
            const float4* ns = px + (c + 1) * CHUNK_F4;   // hides under process
            r0 = ns[t]; r1 = ns[t + 512]; r2 = ns[t + 1024];
        }
        __syncthreads();              // staged data visible

        // process 4 points/thread; xs word-stride 3 (coprime 32) -> no conflicts
        #pragma unroll
        for (int k = 0; k < 4; ++k) {
            const int p = k * THREADS + t;
            const float vx = xs[p * 3 + 0];
            const float vy = xs[p * 3 + 1];
            const float vz = xs[p * 3 + 2];
            const bool ok = (__builtin_fabsf(vx) <= 2.f) &&
                            (__builtin_fabsf(vy) <= 2.f) &&
                            (__builtin_fabsf(vz) <= 2.f);
            // exact reference rounding: (v+2)*2 (exact fp32), trunc==floor,
            // clamp 8 -> 7 (v == HI in last bin); out-of-range gated by ok
            const int ix = min((int)((vx + 2.f) * 2.f), VR - 1);
            const int iy = min((int)((vy + 2.f) * 2.f), VR - 1);
            const int iz = min((int)((vz + 2.f) * 2.f), VR - 1);
            if (ok) atomicAdd(&hist[(ix * VR + iy) * VR + iz], 1u);
        }
    }
    __syncthreads();

    // ---- epilogue (identical to passing kernel) ----
    // 4 lanes per class: t = c*4 + s, c in [0,40), s in [0,4).
    if (t < CLASSES * 4) {
        const int c = t >> 2;
        const int s = t & 3;
        const float* Wc = W + c * BINS;
        float acc = 0.f;
        #pragma unroll 8
        for (int i = 0; i < BINS / 4; ++i) {
            const int v = i * 4 + s;
            acc += (float)hist[v] * Wc[v];
        }
        acc += __shfl_xor(acc, 1);
        acc += __shfl_xor(acc, 2);
        if (s == 0)
            out[b * CLASSES + c] = acc * (1.0f / NPTS) + bias[c];
    }
}

extern "C" void kernel_launch(void* const* d_in, const int* in_sizes, int n_in,
                              void* d_out, int out_size, void* d_ws, size_t ws_size,
                              hipStream_t stream) {
    const float* x    = (const float*)d_in[0];   // (1024, 8192, 3)
    const float* W    = (const float*)d_in[1];   // (40, 512)
    const float* bias = (const float*)d_in[2];   // (40,)
    float* out        = (float*)d_out;           // (1024, 40)

    const int nbatch = in_sizes[0] / (NPTS * 3); // 1024
    voxel_cls_kernel<<<nbatch, THREADS, 0, stream>>>(x, W, bias, out);
}